// Round 6
// baseline (8211504.688 us; speedup 1.0000x reference)
//
#include <hip/hip_runtime.h>

typedef __attribute__((ext_vector_type(8))) short bf16x8;
typedef __attribute__((ext_vector_type(4))) float f32x4;
typedef unsigned short ushort_t;
typedef unsigned int uint_t;

#define VOCAB 5000
#define HID   512
#define B_    64
#define SEQ_  256
#define H3    1536
#define NPAD  5120

__device__ __forceinline__ ushort_t f2bf(float f){
  uint_t u = __float_as_uint(f);
  u = u + 0x7fffu + ((u >> 16) & 1u);
  return (ushort_t)(u >> 16);
}
__device__ __forceinline__ float bf2f(ushort_t s){
  return __uint_as_float(((uint_t)s) << 16);
}

// ---- XCD-local (L2) exchange: plain stores write through L1 to the shared L2;
// ---- loads use sc0 to bypass the per-CU L1 (stale) and read L2 directly.
__device__ __forceinline__ uint_t l2_load_u32(const uint_t* p){
  uint_t v;
  asm volatile("global_load_dword %0, %1, off sc0\n\t"
               "s_waitcnt vmcnt(0)" : "=v"(v) : "v"(p) : "memory");
  return v;
}
__device__ __forceinline__ void l2_store_u32(uint_t* p, uint_t v){
  asm volatile("global_store_dword %0, %1, off sc0" :: "v"(p), "v"(v) : "memory");
}
__device__ __forceinline__ void l2_store_u16(ushort_t* p, ushort_t v){
  uint_t vv = v;
  asm volatile("global_store_short %0, %1, off sc0" :: "v"(p), "v"(vv) : "memory");
}

// ---------------- P1: transpose W_ih (1536 x 5000) -> W_ihT (5000 x 1536) ----------
__global__ void k_transpose(const float* __restrict__ W, float* __restrict__ WT){
  __shared__ float tile[32][33];
  const int bv = blockIdx.x * 32;   // vocab
  const int bg = blockIdx.y * 32;   // 3H
  const int tx = threadIdx.x, ty = threadIdx.y; // 32x8
  #pragma unroll
  for(int r = 0; r < 32; r += 8){
    int g = bg + ty + r, v = bv + tx;
    tile[ty + r][tx] = (v < VOCAB) ? W[(size_t)g * VOCAB + v] : 0.f;
  }
  __syncthreads();
  #pragma unroll
  for(int r = 0; r < 32; r += 8){
    int v = bv + ty + r, g = bg + tx;
    if(v < VOCAB) WT[(size_t)v * H3 + g] = tile[tx][ty + r];
  }
}

// ---------------- P1b: W_out (5000x512) -> bf16 padded (5120x512) ------------------
__global__ void k_cvt_wout(const float* __restrict__ W, ushort_t* __restrict__ WP){
  int idx = (blockIdx.x * 256 + threadIdx.x) * 4;
  if(idx >= NPAD * HID) return;
  float x0 = 0.f, x1 = 0.f, x2 = 0.f, x3 = 0.f;
  if(idx < VOCAB * HID){
    const float4 v = *(const float4*)(W + idx);
    x0 = v.x; x1 = v.y; x2 = v.z; x3 = v.w;
  }
  ushort4 o; o.x = f2bf(x0); o.y = f2bf(x1); o.z = f2bf(x2); o.w = f2bf(x3);
  *(ushort4*)(WP + idx) = o;
}

// ---------------- P2: gather x_proj[s,b,:] = W_ihT[X[b,s]] + b_ih  (bf16 out) ------
__global__ void k_gather(const int* __restrict__ X, const float* __restrict__ WT,
                         const float* __restrict__ bih, ushort_t* __restrict__ xp){
  const int sb = blockIdx.x;            // s*64 + b
  const int s = sb >> 6, b = sb & 63;
  const int x = X[b * SEQ_ + s];
  const float4* src = (const float4*)(WT + (size_t)x * H3);
  const float4* bi  = (const float4*)bih;
  for(int i = threadIdx.x; i < H3 / 4; i += 256){
    float4 v = src[i], c = bi[i];
    ushort4 o;
    o.x = f2bf(v.x + c.x); o.y = f2bf(v.y + c.y);
    o.z = f2bf(v.z + c.z); o.w = f2bf(v.w + c.w);
    ((ushort4*)(xp + (size_t)sb * H3))[i] = o;
  }
}

// ---------------- R: XCD-local GRU recurrence ---------------------------------------
// 256 blocks (1/CU, all co-resident; 32 per XCD). Each block claims a per-XCD slot;
// the 16th claimer on an XCD claims a domain. Domains 0/1 (batches 0-31 / 32-63) run
// entirely on one XCD each; all sync through that XCD's L2 (plain store + sc0 load).
// ctrl layout (uints): [x*32]=slot counters; [256]=domain ticket; [512+x*32]=dom cell;
// [1024 + x*512 + slot*32] = step flags. hslabs: per-XCD 2x32x512 bf16 (64KB each).
__global__ void __launch_bounds__(256, 1) k_rec(
    const float* __restrict__ Whh, const float* __restrict__ bhh,
    const float* __restrict__ state, const ushort_t* __restrict__ xp,
    ushort_t* __restrict__ hslabs, ushort_t* __restrict__ Y,
    float* __restrict__ hT, uint_t* ctrl)
{
  __shared__ ushort_t Wl[96][520];
  __shared__ float bl[96];
  __shared__ int s_dom, s_slot, s_xcd;
  const int tid = threadIdx.x;

  if(tid == 0){
    uint_t x;
    asm volatile("s_getreg_b32 %0, hwreg(HW_REG_XCC_ID)" : "=s"(x));
    x &= 7u;
    uint_t slot = atomicAdd(ctrl + x * 32, 1u);
    int dom = -1;
    if(slot < 16u){
      uint_t* dticket = ctrl + 256;
      uint_t* dcell   = ctrl + 512 + x * 32;
      if(slot == 15u){
        uint_t d = atomicAdd(dticket, 1u);
        __hip_atomic_store(dcell, d + 1u, __ATOMIC_RELAXED, __HIP_MEMORY_SCOPE_AGENT);
        dom = (int)d;
      } else {
        int gd = 0; uint_t v;
        while((v = __hip_atomic_load(dcell, __ATOMIC_RELAXED, __HIP_MEMORY_SCOPE_AGENT)) == 0u){
          if(++gd > 1000000) break;
        }
        dom = (int)v - 1;
      }
    }
    s_dom = (slot < 16u && dom >= 0 && dom < 2) ? dom : -1;
    s_slot = (int)slot;
    s_xcd = (int)x;
  }
  __syncthreads();
  const int dom = s_dom, slot = s_slot, xcd = s_xcd;
  if(dom < 0) return;

  const int jb = slot * 32;
  for(int idx = tid; idx < 96 * 512; idx += 256){
    int r = idx >> 9, c = idx & 511;
    int jgr = r / 48, rem = r % 48;
    int gate = rem >> 4, jl = jgr * 16 + (rem & 15);
    Wl[r][c] = f2bf(Whh[((size_t)(gate * HID + jb + jl)) * HID + c]);
  }
  if(tid < 96){
    int jgr = tid / 48, rem = tid % 48;
    int gate = rem >> 4, jl = jgr * 16 + (rem & 15);
    bl[tid] = bhh[gate * HID + jb + jl];
  }

  const int lane = tid & 63, wv = tid >> 6;
  const int l15 = lane & 15, lhi = lane >> 4;
  const int jg = wv >> 1;
  const int j  = jb + jg * 16 + l15;
  const int rbase = jg * 48;
  const int lband = (wv & 1) * 16;               // local batch band [0,32)

  ushort_t* hs = hslabs + (size_t)xcd * 32768;   // this XCD's slab
  uint_t* myflag = ctrl + 1024 + xcd * 512 + slot * 32;
  uint_t* flagbase = ctrl + 1024 + xcd * 512;

  float hprev[4]; int lrow[4], brow[4];
  #pragma unroll
  for(int i = 0; i < 4; i++){
    lrow[i] = lband + lhi * 4 + i;
    brow[i] = dom * 32 + lrow[i];
    hprev[i] = state[brow[i] * HID + j];
  }

  #pragma unroll
  for(int i = 0; i < 4; i++) l2_store_u16(hs + lrow[i] * HID + j, f2bf(hprev[i]));
  asm volatile("s_waitcnt vmcnt(0)" ::: "memory");
  __syncthreads();
  if(tid == 0) l2_store_u32(myflag, 1u);

  for(int t = 0; t < SEQ_; ++t){
    const ushort_t* hin  = hs + (t & 1) * 16384;
    ushort_t*       hout = hs + ((t + 1) & 1) * 16384;

    // gi prefetch (bf16 xp), issued before the poll to hide latency
    float gir[4], giz[4], gin_[4];
    const ushort_t* xr = xp + (size_t)t * B_ * H3;
    #pragma unroll
    for(int i = 0; i < 4; i++){
      const ushort_t* p = xr + (size_t)brow[i] * H3 + j;
      gir[i] = bf2f(p[0]); giz[i] = bf2f(p[HID]); gin_[i] = bf2f(p[2 * HID]);
    }

    // wait: all 16 WGs of this domain published h^t (flags in our XCD's L2)
    if(tid < 16){
      const uint_t need = (uint_t)(t + 1);
      int gd = 0;
      while(l2_load_u32(flagbase + tid * 32) < need){
        if(++gd > 400000) break;   // fail loud (wrong answer) instead of hanging
      }
    }
    __syncthreads();

    // read h^t (32 local rows) from the XCD L2
    int4 tmp[16];
    const char* abase = (const char*)(hin + (size_t)(lband + l15) * HID + 8 * lhi);
    #define LDH(i, off) asm volatile("global_load_dwordx4 %0, %1, off offset:" #off " sc0" \
                                     : "=v"(tmp[i]) : "v"(abase) : "memory");
    LDH(0,0)   LDH(1,64)   LDH(2,128)  LDH(3,192)
    LDH(4,256) LDH(5,320)  LDH(6,384)  LDH(7,448)
    LDH(8,512) LDH(9,576)  LDH(10,640) LDH(11,704)
    LDH(12,768) LDH(13,832) LDH(14,896) LDH(15,960)
    #undef LDH
    asm volatile("s_waitcnt vmcnt(0)" ::: "memory");
    __builtin_amdgcn_sched_barrier(0);

    // GEMM: gh_slice = H(16x512) @ Wl^T(512x48) per wave
    f32x4 acc0 = {0.f,0.f,0.f,0.f}, acc1 = {0.f,0.f,0.f,0.f}, acc2 = {0.f,0.f,0.f,0.f};
    #pragma unroll
    for(int kk = 0; kk < 16; kk++){
      bf16x8 a = __builtin_bit_cast(bf16x8, tmp[kk]);
      const int kc = kk * 32 + 8 * lhi;
      bf16x8 b0 = *(const bf16x8*)&Wl[rbase + l15][kc];
      bf16x8 b1 = *(const bf16x8*)&Wl[rbase + 16 + l15][kc];
      bf16x8 b2 = *(const bf16x8*)&Wl[rbase + 32 + l15][kc];
      acc0 = __builtin_amdgcn_mfma_f32_16x16x32_bf16(a, b0, acc0, 0, 0, 0);
      acc1 = __builtin_amdgcn_mfma_f32_16x16x32_bf16(a, b1, acc1, 0, 0, 0);
      acc2 = __builtin_amdgcn_mfma_f32_16x16x32_bf16(a, b2, acc2, 0, 0, 0);
    }

    const float cr = bl[rbase + l15], cz = bl[rbase + 16 + l15], cn = bl[rbase + 32 + l15];
    #pragma unroll
    for(int i = 0; i < 4; i++){
      float r = 1.f / (1.f + expf(-(gir[i] + acc0[i] + cr)));
      float z = 1.f / (1.f + expf(-(giz[i] + acc1[i] + cz)));
      float n = tanhf(gin_[i] + r * (acc2[i] + cn));
      float hn = (1.f - z) * n + z * hprev[i];
      hprev[i] = hn;
      ushort_t hb = f2bf(hn);
      l2_store_u16(hout + (size_t)lrow[i] * HID + j, hb);
      Y[(size_t)t * B_ * HID + (size_t)brow[i] * HID + j] = hb;   // normal cached store
      if(t == SEQ_ - 1) hT[brow[i] * HID + j] = hn;
    }
    asm volatile("s_waitcnt vmcnt(0)" ::: "memory");
    __syncthreads();
    if(tid == 0) l2_store_u32(myflag, (uint_t)(t + 2));
  }
}

// ---------------- C: out = Y(16384x512) @ W_outP^T(512x5120) + b_out ---------------
__global__ void __launch_bounds__(256) k_outgemm(
    const ushort_t* __restrict__ Y, const ushort_t* __restrict__ WP,
    const float* __restrict__ bout, float* __restrict__ out)
{
  __shared__ ushort_t At[128][40];
  __shared__ ushort_t Bt[128][40];
  const int tid = threadIdx.x;
  const int sb0 = blockIdx.x * 128, n0 = blockIdx.y * 128;
  const int lane = tid & 63, wv = tid >> 6;
  const int l15 = lane & 15, lhi = lane >> 4;
  const int wm = wv >> 1, wn = wv & 1;

  f32x4 acc[4][4];
  #pragma unroll
  for(int a = 0; a < 4; a++)
    #pragma unroll
    for(int b = 0; b < 4; b++) acc[a][b] = (f32x4){0.f,0.f,0.f,0.f};

  for(int kt = 0; kt < 16; ++kt){
    const int k0 = kt * 32;
    __syncthreads();
    #pragma unroll
    for(int hh = 0; hh < 2; ++hh){
      int idx = tid + hh * 256;          // 0..511 over 128 rows x 4 segs
      int row = idx >> 2, seg = idx & 3;
      int4 va = *(const int4*)(Y  + (size_t)(sb0 + row) * HID + k0 + seg * 8);
      *(int4*)&At[row][seg * 8] = va;
      int4 vb = *(const int4*)(WP + (size_t)(n0 + row) * HID + k0 + seg * 8);
      *(int4*)&Bt[row][seg * 8] = vb;
    }
    __syncthreads();
    bf16x8 a[4], b[4];
    #pragma unroll
    for(int mi = 0; mi < 4; mi++) a[mi] = *(const bf16x8*)&At[wm * 64 + mi * 16 + l15][8 * lhi];
    #pragma unroll
    for(int ni = 0; ni < 4; ni++) b[ni] = *(const bf16x8*)&Bt[wn * 64 + ni * 16 + l15][8 * lhi];
    #pragma unroll
    for(int mi = 0; mi < 4; mi++)
      #pragma unroll
      for(int ni = 0; ni < 4; ni++)
        acc[mi][ni] = __builtin_amdgcn_mfma_f32_16x16x32_bf16(a[mi], b[ni], acc[mi][ni], 0, 0, 0);
  }

  #pragma unroll
  for(int mi = 0; mi < 4; mi++){
    #pragma unroll
    for(int ni = 0; ni < 4; ni++){
      int v = n0 + wn * 64 + ni * 16 + l15;
      if(v < VOCAB){
        float bb = bout[v];
        #pragma unroll
        for(int i = 0; i < 4; i++){
          int sb = sb0 + wm * 64 + mi * 16 + lhi * 4 + i;
          out[(size_t)sb * VOCAB + v] = acc[mi][ni][i] + bb;
        }
      }
    }
  }
}

extern "C" void kernel_launch(void* const* d_in, const int* in_sizes, int n_in,
                              void* d_out, int out_size, void* d_ws, size_t ws_size,
                              hipStream_t stream)
{
  const int*   X     = (const int*)  d_in[0];
  const float* state = (const float*)d_in[1];
  const float* Wih   = (const float*)d_in[2];
  const float* Whh   = (const float*)d_in[3];
  const float* bih   = (const float*)d_in[4];
  const float* bhh   = (const float*)d_in[5];
  const float* Wout  = (const float*)d_in[6];
  const float* bout  = (const float*)d_in[7];
  float* out = (float*)d_out;
  float* hT  = out + (size_t)SEQ_ * B_ * VOCAB;

  char* ws = (char*)d_ws;
  const size_t off_hsl   = 32768;                                   // 512 KB of slabs
  const size_t off_WihT  = off_hsl   + (size_t)8 * 65536;
  const size_t off_WoutP = off_WihT  + (size_t)VOCAB * H3  * sizeof(float);
  const size_t off_Y     = off_WoutP + (size_t)NPAD  * HID * sizeof(ushort_t);
  const size_t off_xp    = off_Y     + (size_t)SEQ_ * B_ * HID * sizeof(ushort_t);

  uint_t*   ctrl   = (uint_t*)  ws;
  ushort_t* hslabs = (ushort_t*)(ws + off_hsl);
  float*    WihT   = (float*)   (ws + off_WihT);
  ushort_t* WoutP  = (ushort_t*)(ws + off_WoutP);
  ushort_t* Ybuf   = (ushort_t*)(ws + off_Y);
  ushort_t* xp     = (ushort_t*)(ws + off_xp);

  hipMemsetAsync(d_ws, 0, 32768, stream);
  hipLaunchKernelGGL(k_transpose, dim3(157, 48), dim3(32, 8), 0, stream, Wih, WihT);
  hipLaunchKernelGGL(k_cvt_wout, dim3((NPAD * HID / 4 + 255) / 256), dim3(256), 0, stream, Wout, WoutP);
  hipLaunchKernelGGL(k_gather, dim3(SEQ_ * B_), dim3(256), 0, stream, X, WihT, bih, xp);
  hipLaunchKernelGGL(k_rec, dim3(256), dim3(256), 0, stream,
                     Whh, bhh, state, xp, hslabs, Ybuf, hT, ctrl);
  hipLaunchKernelGGL(k_outgemm, dim3(128, 40), dim3(256), 0, stream, Ybuf, WoutP, bout, out);
}

// Round 8
// 347852.612 us; speedup vs baseline: 23.6063x; 23.6063x over previous
//
#include <hip/hip_runtime.h>

typedef __attribute__((ext_vector_type(8))) short bf16x8;
typedef __attribute__((ext_vector_type(4))) float f32x4;
typedef __attribute__((ext_vector_type(4))) int i32x4;
typedef unsigned short ushort_t;
typedef unsigned int uint_t;

#define VOCAB 5000
#define HID   512
#define B_    64
#define SEQ_  256
#define H3    1536
#define NPAD  5120
#define NREC  32

__device__ __forceinline__ ushort_t f2bf(float f){
  uint_t u = __float_as_uint(f);
  u = u + 0x7fffu + ((u >> 16) & 1u);
  return (ushort_t)(u >> 16);
}
__device__ __forceinline__ float bf2f(ushort_t s){
  return __uint_as_float(((uint_t)s) << 16);
}

// ---------------- P1: transpose W_ih (1536 x 5000) -> W_ihT (5000 x 1536) ----------
__global__ void k_transpose(const float* __restrict__ W, float* __restrict__ WT){
  __shared__ float tile[32][33];
  const int bv = blockIdx.x * 32;   // vocab
  const int bg = blockIdx.y * 32;   // 3H
  const int tx = threadIdx.x, ty = threadIdx.y; // 32x8
  #pragma unroll
  for(int r = 0; r < 32; r += 8){
    int g = bg + ty + r, v = bv + tx;
    tile[ty + r][tx] = (v < VOCAB) ? W[(size_t)g * VOCAB + v] : 0.f;
  }
  __syncthreads();
  #pragma unroll
  for(int r = 0; r < 32; r += 8){
    int v = bv + ty + r, g = bg + tx;
    if(v < VOCAB) WT[(size_t)v * H3 + g] = tile[tx][ty + r];
  }
}

// ---------------- P1b: W_out (5000x512) -> bf16 padded (5120x512) ------------------
__global__ void k_cvt_wout(const float* __restrict__ W, ushort_t* __restrict__ WP){
  int idx = (blockIdx.x * 256 + threadIdx.x) * 4;
  if(idx >= NPAD * HID) return;
  float x0 = 0.f, x1 = 0.f, x2 = 0.f, x3 = 0.f;
  if(idx < VOCAB * HID){
    const float4 v = *(const float4*)(W + idx);
    x0 = v.x; x1 = v.y; x2 = v.z; x3 = v.w;
  }
  ushort4 o; o.x = f2bf(x0); o.y = f2bf(x1); o.z = f2bf(x2); o.w = f2bf(x3);
  *(ushort4*)(WP + idx) = o;
}

// ---------------- P2: gather x_proj[s,b,:] = W_ihT[X[b,s]] + b_ih  (bf16 out) ------
__global__ void k_gather(const int* __restrict__ X, const float* __restrict__ WT,
                         const float* __restrict__ bih, ushort_t* __restrict__ xp){
  const int sb = blockIdx.x;            // s*64 + b
  const int s = sb >> 6, b = sb & 63;
  const int x = X[b * SEQ_ + s];
  const float4* src = (const float4*)(WT + (size_t)x * H3);
  const float4* bi  = (const float4*)bih;
  for(int i = threadIdx.x; i < H3 / 4; i += 256){
    float4 v = src[i], c = bi[i];
    ushort4 o;
    o.x = f2bf(v.x + c.x); o.y = f2bf(v.y + c.y);
    o.z = f2bf(v.z + c.z); o.w = f2bf(v.w + c.w);
    ((ushort4*)(xp + (size_t)sb * H3))[i] = o;
  }
}

// ---------------- R: seqlock GRU recurrence, 32 WGs, barrier-free steps ------------
// hbuf is u32[2][64][512]: (h_bf16 << 16) | tag, tag = publication index + 1.
// Publication k (k=0: init from state; k=t+1 after step t) -> buffer k&1, tag k+1.
// Producers: one global_store_dwordx4 sc1 per lane (4 consecutive j of one batch,
// post intra-wave LDS transpose). Consumers: poll chunks until all tags == t+1.
// No flags, no drains, no per-step __syncthreads -- pure dataflow, drift <= 1 step.
__global__ void __launch_bounds__(256, 1) k_rec(
    const float* __restrict__ Whh, const float* __restrict__ bhh,
    const float* __restrict__ state, const ushort_t* __restrict__ xp,
    uint_t* __restrict__ hb,       // u32 [2][64][512], zeroed before launch
    ushort_t* __restrict__ Y,      // [256][64][512] bf16
    float* __restrict__ hT)        // d_out tail
{
  __shared__ ushort_t Wl[96][520];
  __shared__ float bl[96];
  __shared__ ushort_t tsc[4][16][20];   // per-wave transpose scratch
  const int g = blockIdx.x, tid = threadIdx.x;
  const int dom = g >> 4, sub = g & 15;
  const int jb = sub * 32;

  for(int idx = tid; idx < 96 * 512; idx += 256){
    int r = idx >> 9, c = idx & 511;
    int jgr = r / 48, rem = r % 48;
    int gate = rem >> 4, jl = jgr * 16 + (rem & 15);
    Wl[r][c] = f2bf(Whh[((size_t)(gate * HID + jb + jl)) * HID + c]);
  }
  if(tid < 96){
    int jgr = tid / 48, rem = tid % 48;
    int gate = rem >> 4, jl = jgr * 16 + (rem & 15);
    bl[tid] = bhh[gate * HID + jb + jl];
  }
  __syncthreads();   // the only block-wide barrier; waves free-run afterwards

  const int lane = tid & 63, wv = tid >> 6;
  const int l15 = lane & 15, lhi = lane >> 4;
  const int jg = wv >> 1;
  const int jt0 = jb + jg * 16;
  const int j  = jt0 + l15;
  const int rbase = jg * 48;
  const int bband = dom * 32 + (wv & 1) * 16;

  float hprev[4]; int brow[4];
  #pragma unroll
  for(int i = 0; i < 4; i++){
    brow[i] = bband + lhi * 4 + i;
    hprev[i] = state[brow[i] * HID + j];
  }

  // ---- initial publication (k=0, tag 1, buffer 0) ----
  #pragma unroll
  for(int i = 0; i < 4; i++) tsc[wv][lhi * 4 + i][l15] = f2bf(hprev[i]);
  asm volatile("s_waitcnt lgkmcnt(0)" ::: "memory");
  {
    uint2 rv = *(const uint2*)&tsc[wv][l15][lhi * 4];
    i32x4 st_;
    st_[0] = (int)((rv.x << 16) | 1u);
    st_[1] = (int)((rv.x & 0xffff0000u) | 1u);
    st_[2] = (int)((rv.y << 16) | 1u);
    st_[3] = (int)((rv.y & 0xffff0000u) | 1u);
    uint_t* dst_ = hb + (size_t)(bband + l15) * HID + (jt0 + lhi * 4);
    asm volatile("global_store_dwordx4 %0, %1, off sc1" :: "v"(dst_), "v"(st_) : "memory");
  }

  #define CHK4(c) (((uint_t)(c)[0] ^ need_) | ((uint_t)(c)[1] ^ need_) | \
                   ((uint_t)(c)[2] ^ need_) | ((uint_t)(c)[3] ^ need_))
  #define MKFRAG(dstf, lo, hi) { \
    union { i32x4 q; bf16x8 v; } u_; \
    u_.q[0] = (int)__builtin_amdgcn_perm((uint_t)(lo)[1], (uint_t)(lo)[0], 0x07060302u); \
    u_.q[1] = (int)__builtin_amdgcn_perm((uint_t)(lo)[3], (uint_t)(lo)[2], 0x07060302u); \
    u_.q[2] = (int)__builtin_amdgcn_perm((uint_t)(hi)[1], (uint_t)(hi)[0], 0x07060302u); \
    u_.q[3] = (int)__builtin_amdgcn_perm((uint_t)(hi)[3], (uint_t)(hi)[2], 0x07060302u); \
    dstf = u_.v; }

  #define GROUP(GRP) { \
    const char* gb_ = rowbase + (GRP) * 512 + lhi * 32; \
    i32x4 c0, c1, c2, c3, c4, c5, c6, c7; \
    int gd_ = 0; \
    while(true){ \
      asm volatile("global_load_dwordx4 %0, %8, off sc1\n\t" \
                   "global_load_dwordx4 %1, %8, off offset:16 sc1\n\t" \
                   "global_load_dwordx4 %2, %8, off offset:128 sc1\n\t" \
                   "global_load_dwordx4 %3, %8, off offset:144 sc1\n\t" \
                   "global_load_dwordx4 %4, %8, off offset:256 sc1\n\t" \
                   "global_load_dwordx4 %5, %8, off offset:272 sc1\n\t" \
                   "global_load_dwordx4 %6, %8, off offset:384 sc1\n\t" \
                   "global_load_dwordx4 %7, %8, off offset:400 sc1\n\t" \
                   "s_waitcnt vmcnt(0)" \
                   : "=&v"(c0), "=&v"(c1), "=&v"(c2), "=&v"(c3), \
                     "=&v"(c4), "=&v"(c5), "=&v"(c6), "=&v"(c7) \
                   : "v"(gb_) : "memory"); \
      uint_t bad_ = (CHK4(c0) | CHK4(c1) | CHK4(c2) | CHK4(c3) | \
                     CHK4(c4) | CHK4(c5) | CHK4(c6) | CHK4(c7)) & 0xffffu; \
      if(__all(bad_ == 0)) break; \
      if(++gd_ > 100000) break; \
    } \
    __builtin_amdgcn_sched_barrier(0); \
    bf16x8 a0, a1, a2, a3; \
    MKFRAG(a0, c0, c1) MKFRAG(a1, c2, c3) MKFRAG(a2, c4, c5) MKFRAG(a3, c6, c7) \
    _Pragma("unroll") \
    for(int kl = 0; kl < 4; kl++){ \
      bf16x8 a = (kl == 0) ? a0 : (kl == 1) ? a1 : (kl == 2) ? a2 : a3; \
      const int kc = ((GRP) * 4 + kl) * 32 + 8 * lhi; \
      bf16x8 b0 = *(const bf16x8*)&Wl[rbase + l15][kc]; \
      bf16x8 b1 = *(const bf16x8*)&Wl[rbase + 16 + l15][kc]; \
      bf16x8 b2 = *(const bf16x8*)&Wl[rbase + 32 + l15][kc]; \
      acc0 = __builtin_amdgcn_mfma_f32_16x16x32_bf16(a, b0, acc0, 0, 0, 0); \
      acc1 = __builtin_amdgcn_mfma_f32_16x16x32_bf16(a, b1, acc1, 0, 0, 0); \
      acc2 = __builtin_amdgcn_mfma_f32_16x16x32_bf16(a, b2, acc2, 0, 0, 0); \
    } }

  for(int t = 0; t < SEQ_; ++t){
    const uint_t* hin = hb + (size_t)(t & 1) * (B_ * HID);
    uint_t*      hout = hb + (size_t)((t + 1) & 1) * (B_ * HID);
    const uint_t need_ = (uint_t)(t + 1);
    const uint_t tag2  = (uint_t)(t + 2);

    // gi prefetch (bf16 xp, cached), issued before the polls
    float gir[4], giz[4], gin_[4];
    const ushort_t* xr = xp + (size_t)t * B_ * H3;
    #pragma unroll
    for(int i = 0; i < 4; i++){
      const ushort_t* p = xr + (size_t)brow[i] * H3 + j;
      gir[i] = bf2f(p[0]); giz[i] = bf2f(p[HID]); gin_[i] = bf2f(p[2 * HID]);
    }

    const char* rowbase = (const char*)(hin + (size_t)(bband + l15) * HID);
    f32x4 acc0 = {0.f,0.f,0.f,0.f}, acc1 = {0.f,0.f,0.f,0.f}, acc2 = {0.f,0.f,0.f,0.f};
    GROUP(0) GROUP(1) GROUP(2) GROUP(3)

    const float cr = bl[rbase + l15], cz = bl[rbase + 16 + l15], cn = bl[rbase + 32 + l15];
    float hn4[4];
    #pragma unroll
    for(int i = 0; i < 4; i++){
      float r = 1.f / (1.f + expf(-(gir[i] + acc0[i] + cr)));
      float z = 1.f / (1.f + expf(-(giz[i] + acc1[i] + cz)));
      float n = tanhf(gin_[i] + r * (acc2[i] + cn));
      hn4[i] = (1.f - z) * n + z * hprev[i];
      hprev[i] = hn4[i];
    }

    // intra-wave transpose: (4 batches x 1 j) -> (1 batch x 4 consecutive j)
    #pragma unroll
    for(int i = 0; i < 4; i++) tsc[wv][lhi * 4 + i][l15] = f2bf(hn4[i]);
    asm volatile("s_waitcnt lgkmcnt(0)" ::: "memory");
    uint2 rv = *(const uint2*)&tsc[wv][l15][lhi * 4];

    i32x4 st_;
    st_[0] = (int)((rv.x << 16) | tag2);
    st_[1] = (int)((rv.x & 0xffff0000u) | tag2);
    st_[2] = (int)((rv.y << 16) | tag2);
    st_[3] = (int)((rv.y & 0xffff0000u) | tag2);
    uint_t* dst_ = hout + (size_t)(bband + l15) * HID + (jt0 + lhi * 4);
    asm volatile("global_store_dwordx4 %0, %1, off sc1" :: "v"(dst_), "v"(st_) : "memory");

    // off the critical path: Y (8B contiguous, cached) and final hT
    *(uint2*)(Y + (size_t)t * B_ * HID + (size_t)(bband + l15) * HID + jt0 + lhi * 4) = rv;
    if(t == SEQ_ - 1){
      #pragma unroll
      for(int i = 0; i < 4; i++) hT[brow[i] * HID + j] = hn4[i];
    }
  }
  #undef GROUP
  #undef MKFRAG
  #undef CHK4
}

// ---------------- C: out = Y(16384x512) @ W_outP^T(512x5120) + b_out ---------------
__global__ void __launch_bounds__(256) k_outgemm(
    const ushort_t* __restrict__ Y, const ushort_t* __restrict__ WP,
    const float* __restrict__ bout, float* __restrict__ out)
{
  __shared__ ushort_t At[128][40];
  __shared__ ushort_t Bt[128][40];
  const int tid = threadIdx.x;
  const int sb0 = blockIdx.x * 128, n0 = blockIdx.y * 128;
  const int lane = tid & 63, wv = tid >> 6;
  const int l15 = lane & 15, lhi = lane >> 4;
  const int wm = wv >> 1, wn = wv & 1;

  f32x4 acc[4][4];
  #pragma unroll
  for(int a = 0; a < 4; a++)
    #pragma unroll
    for(int b = 0; b < 4; b++) acc[a][b] = (f32x4){0.f,0.f,0.f,0.f};

  for(int kt = 0; kt < 16; ++kt){
    const int k0 = kt * 32;
    __syncthreads();
    #pragma unroll
    for(int hh = 0; hh < 2; ++hh){
      int idx = tid + hh * 256;          // 0..511 over 128 rows x 4 segs
      int row = idx >> 2, seg = idx & 3;
      int4 va = *(const int4*)(Y  + (size_t)(sb0 + row) * HID + k0 + seg * 8);
      *(int4*)&At[row][seg * 8] = va;
      int4 vb = *(const int4*)(WP + (size_t)(n0 + row) * HID + k0 + seg * 8);
      *(int4*)&Bt[row][seg * 8] = vb;
    }
    __syncthreads();
    bf16x8 a[4], b[4];
    #pragma unroll
    for(int mi = 0; mi < 4; mi++) a[mi] = *(const bf16x8*)&At[wm * 64 + mi * 16 + l15][8 * lhi];
    #pragma unroll
    for(int ni = 0; ni < 4; ni++) b[ni] = *(const bf16x8*)&Bt[wn * 64 + ni * 16 + l15][8 * lhi];
    #pragma unroll
    for(int mi = 0; mi < 4; mi++)
      #pragma unroll
      for(int ni = 0; ni < 4; ni++)
        acc[mi][ni] = __builtin_amdgcn_mfma_f32_16x16x32_bf16(a[mi], b[ni], acc[mi][ni], 0, 0, 0);
  }

  #pragma unroll
  for(int mi = 0; mi < 4; mi++){
    #pragma unroll
    for(int ni = 0; ni < 4; ni++){
      int v = n0 + wn * 64 + ni * 16 + l15;
      if(v < VOCAB){
        float bb = bout[v];
        #pragma unroll
        for(int i = 0; i < 4; i++){
          int sb = sb0 + wm * 64 + mi * 16 + lhi * 4 + i;
          out[(size_t)sb * VOCAB + v] = acc[mi][ni][i] + bb;
        }
      }
    }
  }
}

extern "C" void kernel_launch(void* const* d_in, const int* in_sizes, int n_in,
                              void* d_out, int out_size, void* d_ws, size_t ws_size,
                              hipStream_t stream)
{
  const int*   X     = (const int*)  d_in[0];
  const float* state = (const float*)d_in[1];
  const float* Wih   = (const float*)d_in[2];
  const float* Whh   = (const float*)d_in[3];
  const float* bih   = (const float*)d_in[4];
  const float* bhh   = (const float*)d_in[5];
  const float* Wout  = (const float*)d_in[6];
  const float* bout  = (const float*)d_in[7];
  float* out = (float*)d_out;
  float* hT  = out + (size_t)SEQ_ * B_ * VOCAB;

  char* ws = (char*)d_ws;
  const size_t sz_hbuf   = (size_t)2 * B_ * HID * sizeof(uint_t);    // 256 KB
  const size_t off_WihT  = sz_hbuf;
  const size_t off_WoutP = off_WihT  + (size_t)VOCAB * H3  * sizeof(float);
  const size_t off_Y     = off_WoutP + (size_t)NPAD  * HID * sizeof(ushort_t);
  const size_t off_xp    = off_Y     + (size_t)SEQ_ * B_ * HID * sizeof(ushort_t);

  uint_t*   hbuf  = (uint_t*)  ws;
  float*    WihT  = (float*)   (ws + off_WihT);
  ushort_t* WoutP = (ushort_t*)(ws + off_WoutP);
  ushort_t* Ybuf  = (ushort_t*)(ws + off_Y);
  ushort_t* xp    = (ushort_t*)(ws + off_xp);

  (void)hipMemsetAsync(hbuf, 0, sz_hbuf, stream);   // clear stale seqlock tags
  hipLaunchKernelGGL(k_transpose, dim3(157, 48), dim3(32, 8), 0, stream, Wih, WihT);
  hipLaunchKernelGGL(k_cvt_wout, dim3((NPAD * HID / 4 + 255) / 256), dim3(256), 0, stream, Wout, WoutP);
  hipLaunchKernelGGL(k_gather, dim3(SEQ_ * B_), dim3(256), 0, stream, X, WihT, bih, xp);
  hipLaunchKernelGGL(k_rec, dim3(NREC), dim3(256), 0, stream,
                     Whh, bhh, state, xp, hbuf, Ybuf, hT);
  hipLaunchKernelGGL(k_outgemm, dim3(128, 40), dim3(256), 0, stream, Ybuf, WoutP, bout, out);
}

// Round 9
// 1442.495 us; speedup vs baseline: 5692.5716x; 241.1465x over previous
//
#include <hip/hip_runtime.h>

typedef __attribute__((ext_vector_type(8))) short bf16x8;
typedef __attribute__((ext_vector_type(4))) float f32x4;
typedef __attribute__((ext_vector_type(4))) int i32x4;
typedef unsigned short ushort_t;
typedef unsigned int uint_t;

#define VOCAB 5000
#define HID   512
#define B_    64
#define SEQ_  256
#define H3    1536
#define NPAD  5120
#define NREC  32

__device__ __forceinline__ ushort_t f2bf(float f){
  uint_t u = __float_as_uint(f);
  u = u + 0x7fffu + ((u >> 16) & 1u);
  return (ushort_t)(u >> 16);
}
__device__ __forceinline__ float bf2f(ushort_t s){
  return __uint_as_float(((uint_t)s) << 16);
}

// ---- agent-scope (sc1) helpers: the PROVEN cross-XCD visible flavor (R2/R5) ----
__device__ __forceinline__ uint_t agent_load_u32(const uint_t* p){
  uint_t v;
  asm volatile("global_load_dword %0, %1, off sc1\n\t"
               "s_waitcnt vmcnt(0)" : "=v"(v) : "v"(p) : "memory");
  return v;
}
__device__ __forceinline__ void agent_store_u32(uint_t* p, uint_t v){
  asm volatile("global_store_dword %0, %1, off sc1" :: "v"(p), "v"(v) : "memory");
}
__device__ __forceinline__ void agent_store_u16(ushort_t* p, ushort_t v){
  uint_t vv = v;
  asm volatile("global_store_short %0, %1, off sc1" :: "v"(p), "v"(vv) : "memory");
}

// ---------------- P1: transpose W_ih (1536 x 5000) -> W_ihT (5000 x 1536) ----------
__global__ void k_transpose(const float* __restrict__ W, float* __restrict__ WT){
  __shared__ float tile[32][33];
  const int bv = blockIdx.x * 32;   // vocab
  const int bg = blockIdx.y * 32;   // 3H
  const int tx = threadIdx.x, ty = threadIdx.y; // 32x8
  #pragma unroll
  for(int r = 0; r < 32; r += 8){
    int g = bg + ty + r, v = bv + tx;
    tile[ty + r][tx] = (v < VOCAB) ? W[(size_t)g * VOCAB + v] : 0.f;
  }
  __syncthreads();
  #pragma unroll
  for(int r = 0; r < 32; r += 8){
    int v = bv + ty + r, g = bg + tx;
    if(v < VOCAB) WT[(size_t)v * H3 + g] = tile[tx][ty + r];
  }
}

// ---------------- P1b: W_out (5000x512) -> bf16 padded (5120x512) ------------------
__global__ void k_cvt_wout(const float* __restrict__ W, ushort_t* __restrict__ WP){
  int idx = (blockIdx.x * 256 + threadIdx.x) * 4;
  if(idx >= NPAD * HID) return;
  float x0 = 0.f, x1 = 0.f, x2 = 0.f, x3 = 0.f;
  if(idx < VOCAB * HID){
    const float4 v = *(const float4*)(W + idx);
    x0 = v.x; x1 = v.y; x2 = v.z; x3 = v.w;
  }
  ushort4 o; o.x = f2bf(x0); o.y = f2bf(x1); o.z = f2bf(x2); o.w = f2bf(x3);
  *(ushort4*)(WP + idx) = o;
}

// ---------------- P2: gather x_proj[s,b,:] = W_ihT[X[b,s]] + b_ih  (bf16 out) ------
__global__ void k_gather(const int* __restrict__ X, const float* __restrict__ WT,
                         const float* __restrict__ bih, ushort_t* __restrict__ xp){
  const int sb = blockIdx.x;            // s*64 + b
  const int s = sb >> 6, b = sb & 63;
  const int x = X[b * SEQ_ + s];
  const float4* src = (const float4*)(WT + (size_t)x * H3);
  const float4* bi  = (const float4*)bih;
  for(int i = threadIdx.x; i < H3 / 4; i += 256){
    float4 v = src[i], c = bi[i];
    ushort4 o;
    o.x = f2bf(v.x + c.x); o.y = f2bf(v.y + c.y);
    o.z = f2bf(v.z + c.z); o.w = f2bf(v.w + c.w);
    ((ushort4*)(xp + (size_t)sb * H3))[i] = o;
  }
}

// ---------------- R: persistent GRU recurrence, 2 domains x 16 WGs -----------------
// R5 protocol (proven): scalar sc1 h-stores -> vmcnt(0) -> barrier -> sc1 flag;
// consumers sc1-poll flags then sc1 dwordx4 h-reads. R9 micro-opts:
//  - every wave polls for itself (one barrier/step instead of two)
//  - s_sleep(1) backoff + staggered flag assignment in the poll
//  - Y/hT stores moved AFTER the flag (off the drain's critical path)
__global__ void __launch_bounds__(256, 1) k_rec(
    const float* __restrict__ Whh, const float* __restrict__ bhh,
    const float* __restrict__ state, const ushort_t* __restrict__ xp,
    ushort_t* __restrict__ hbuf,   // 2 x [64][512] bf16 (double buffer)
    ushort_t* __restrict__ Y,      // [256][64][512] bf16
    float* __restrict__ hT,        // d_out tail
    uint_t* flags)                 // 32 flags, stride 32 uints (128B), zeroed
{
  __shared__ ushort_t Wl[96][520];
  __shared__ float bl[96];
  const int g = blockIdx.x, tid = threadIdx.x;
  const int dom = g >> 4, sub = g & 15;
  const int jb = sub * 32;

  for(int idx = tid; idx < 96 * 512; idx += 256){
    int r = idx >> 9, c = idx & 511;
    int jgr = r / 48, rem = r % 48;
    int gate = rem >> 4, jl = jgr * 16 + (rem & 15);
    Wl[r][c] = f2bf(Whh[((size_t)(gate * HID + jb + jl)) * HID + c]);
  }
  if(tid < 96){
    int jgr = tid / 48, rem = tid % 48;
    int gate = rem >> 4, jl = jgr * 16 + (rem & 15);
    bl[tid] = bhh[gate * HID + jb + jl];
  }

  const int lane = tid & 63, wv = tid >> 6;
  const int l15 = lane & 15, lhi = lane >> 4;
  const int jg = wv >> 1;
  const int j  = jb + jg * 16 + l15;
  const int rbase = jg * 48;
  const int bband = dom * 32 + (wv & 1) * 16;

  float hprev[4]; int brow[4];
  #pragma unroll
  for(int i = 0; i < 4; i++){
    brow[i] = bband + lhi * 4 + i;
    hprev[i] = state[brow[i] * HID + j];
  }

  #pragma unroll
  for(int i = 0; i < 4; i++) agent_store_u16(hbuf + brow[i] * HID + j, f2bf(hprev[i]));
  asm volatile("s_waitcnt vmcnt(0)" ::: "memory");
  __syncthreads();
  if(tid == 0) agent_store_u32(flags + g * 32, 1u);

  // staggered flag index for this lane's poll duty
  const int fidx = dom * 16 + ((lane + sub) & 15);

  for(int t = 0; t < SEQ_; ++t){
    const ushort_t* hin  = hbuf + (t & 1) * (B_ * HID);
    ushort_t*       hout = hbuf + ((t + 1) & 1) * (B_ * HID);

    // gi prefetch (bf16 xp, cached); drained by the poll's first vmcnt (hidden)
    float gir[4], giz[4], gin_[4];
    const ushort_t* xr = xp + (size_t)t * B_ * H3;
    #pragma unroll
    for(int i = 0; i < 4; i++){
      const ushort_t* p = xr + (size_t)brow[i] * H3 + j;
      gir[i] = bf2f(p[0]); giz[i] = bf2f(p[HID]); gin_[i] = bf2f(p[2 * HID]);
    }

    // every wave polls all 16 domain flags itself (no barrier after)
    if(lane < 16){
      const uint_t need = (uint_t)(t + 1);
      int gd = 0;
      while(agent_load_u32(flags + fidx * 32) < need){
        __builtin_amdgcn_s_sleep(1);
        if(++gd > 200000) break;   // fail loud (wrong answer) instead of hanging
      }
    }

    // read h^t (32 batches of this domain) from the coherence point
    i32x4 tmp[16];
    const char* abase = (const char*)(hin + (size_t)(bband + l15) * HID + 8 * lhi);
    #define LDH(i, off) asm volatile("global_load_dwordx4 %0, %1, off offset:" #off " sc1" \
                                     : "=v"(tmp[i]) : "v"(abase) : "memory");
    LDH(0,0)   LDH(1,64)   LDH(2,128)  LDH(3,192)
    LDH(4,256) LDH(5,320)  LDH(6,384)  LDH(7,448)
    LDH(8,512) LDH(9,576)  LDH(10,640) LDH(11,704)
    LDH(12,768) LDH(13,832) LDH(14,896) LDH(15,960)
    #undef LDH
    asm volatile("s_waitcnt vmcnt(0)" ::: "memory");
    __builtin_amdgcn_sched_barrier(0);

    // GEMM: gh_slice = H(16x512) @ Wl^T(512x48) per wave
    f32x4 acc0 = {0.f,0.f,0.f,0.f}, acc1 = {0.f,0.f,0.f,0.f}, acc2 = {0.f,0.f,0.f,0.f};
    #pragma unroll
    for(int kk = 0; kk < 16; kk++){
      bf16x8 a = __builtin_bit_cast(bf16x8, tmp[kk]);
      const int kc = kk * 32 + 8 * lhi;
      bf16x8 b0 = *(const bf16x8*)&Wl[rbase + l15][kc];
      bf16x8 b1 = *(const bf16x8*)&Wl[rbase + 16 + l15][kc];
      bf16x8 b2 = *(const bf16x8*)&Wl[rbase + 32 + l15][kc];
      acc0 = __builtin_amdgcn_mfma_f32_16x16x32_bf16(a, b0, acc0, 0, 0, 0);
      acc1 = __builtin_amdgcn_mfma_f32_16x16x32_bf16(a, b1, acc1, 0, 0, 0);
      acc2 = __builtin_amdgcn_mfma_f32_16x16x32_bf16(a, b2, acc2, 0, 0, 0);
    }

    const float cr = bl[rbase + l15], cz = bl[rbase + 16 + l15], cn = bl[rbase + 32 + l15];
    float hn4[4]; ushort_t hb4[4];
    #pragma unroll
    for(int i = 0; i < 4; i++){
      float r = 1.f / (1.f + expf(-(gir[i] + acc0[i] + cr)));
      float z = 1.f / (1.f + expf(-(giz[i] + acc1[i] + cz)));
      float n = tanhf(gin_[i] + r * (acc2[i] + cn));
      hn4[i] = (1.f - z) * n + z * hprev[i];
      hprev[i] = hn4[i];
      hb4[i] = f2bf(hn4[i]);
      agent_store_u16(hout + (size_t)brow[i] * HID + j, hb4[i]);
    }
    asm volatile("s_waitcnt vmcnt(0)" ::: "memory");   // drain only the 4 h-stores
    __syncthreads();                                    // the single barrier per step
    if(tid == 0) agent_store_u32(flags + g * 32, (uint_t)(t + 2));

    // off the critical path: Y (and final hT) via normal cached stores
    #pragma unroll
    for(int i = 0; i < 4; i++){
      Y[(size_t)t * B_ * HID + (size_t)brow[i] * HID + j] = hb4[i];
      if(t == SEQ_ - 1) hT[brow[i] * HID + j] = hn4[i];
    }
  }
}

// ---------------- C: out = Y(16384x512) @ W_outP^T(512x5120) + b_out ---------------
__global__ void __launch_bounds__(256) k_outgemm(
    const ushort_t* __restrict__ Y, const ushort_t* __restrict__ WP,
    const float* __restrict__ bout, float* __restrict__ out)
{
  __shared__ ushort_t At[128][40];
  __shared__ ushort_t Bt[128][40];
  const int tid = threadIdx.x;
  const int sb0 = blockIdx.x * 128, n0 = blockIdx.y * 128;
  const int lane = tid & 63, wv = tid >> 6;
  const int l15 = lane & 15, lhi = lane >> 4;
  const int wm = wv >> 1, wn = wv & 1;

  f32x4 acc[4][4];
  #pragma unroll
  for(int a = 0; a < 4; a++)
    #pragma unroll
    for(int b = 0; b < 4; b++) acc[a][b] = (f32x4){0.f,0.f,0.f,0.f};

  for(int kt = 0; kt < 16; ++kt){
    const int k0 = kt * 32;
    __syncthreads();
    #pragma unroll
    for(int hh = 0; hh < 2; ++hh){
      int idx = tid + hh * 256;          // 0..511 over 128 rows x 4 segs
      int row = idx >> 2, seg = idx & 3;
      int4 va = *(const int4*)(Y  + (size_t)(sb0 + row) * HID + k0 + seg * 8);
      *(int4*)&At[row][seg * 8] = va;
      int4 vb = *(const int4*)(WP + (size_t)(n0 + row) * HID + k0 + seg * 8);
      *(int4*)&Bt[row][seg * 8] = vb;
    }
    __syncthreads();
    bf16x8 a[4], b[4];
    #pragma unroll
    for(int mi = 0; mi < 4; mi++) a[mi] = *(const bf16x8*)&At[wm * 64 + mi * 16 + l15][8 * lhi];
    #pragma unroll
    for(int ni = 0; ni < 4; ni++) b[ni] = *(const bf16x8*)&Bt[wn * 64 + ni * 16 + l15][8 * lhi];
    #pragma unroll
    for(int mi = 0; mi < 4; mi++)
      #pragma unroll
      for(int ni = 0; ni < 4; ni++)
        acc[mi][ni] = __builtin_amdgcn_mfma_f32_16x16x32_bf16(a[mi], b[ni], acc[mi][ni], 0, 0, 0);
  }

  #pragma unroll
  for(int mi = 0; mi < 4; mi++){
    #pragma unroll
    for(int ni = 0; ni < 4; ni++){
      int v = n0 + wn * 64 + ni * 16 + l15;
      if(v < VOCAB){
        float bb = bout[v];
        #pragma unroll
        for(int i = 0; i < 4; i++){
          int sb = sb0 + wm * 64 + mi * 16 + lhi * 4 + i;
          out[(size_t)sb * VOCAB + v] = acc[mi][ni][i] + bb;
        }
      }
    }
  }
}

extern "C" void kernel_launch(void* const* d_in, const int* in_sizes, int n_in,
                              void* d_out, int out_size, void* d_ws, size_t ws_size,
                              hipStream_t stream)
{
  const int*   X     = (const int*)  d_in[0];
  const float* state = (const float*)d_in[1];
  const float* Wih   = (const float*)d_in[2];
  const float* Whh   = (const float*)d_in[3];
  const float* bih   = (const float*)d_in[4];
  const float* bhh   = (const float*)d_in[5];
  const float* Wout  = (const float*)d_in[6];
  const float* bout  = (const float*)d_in[7];
  float* out = (float*)d_out;
  float* hT  = out + (size_t)SEQ_ * B_ * VOCAB;

  char* ws = (char*)d_ws;
  const size_t off_WihT  = 4096;
  const size_t off_WoutP = off_WihT  + (size_t)VOCAB * H3  * sizeof(float);
  const size_t off_Y     = off_WoutP + (size_t)NPAD  * HID * sizeof(ushort_t);
  const size_t off_h     = off_Y     + (size_t)SEQ_ * B_ * HID * sizeof(ushort_t);
  const size_t off_xp    = off_h     + (size_t)2 * B_ * HID * sizeof(ushort_t);

  uint_t*   flags = (uint_t*)  ws;                 // 32 flags, 128B apart (4KB)
  float*    WihT  = (float*)   (ws + off_WihT);
  ushort_t* WoutP = (ushort_t*)(ws + off_WoutP);
  ushort_t* Ybuf  = (ushort_t*)(ws + off_Y);
  ushort_t* hbuf  = (ushort_t*)(ws + off_h);
  ushort_t* xp    = (ushort_t*)(ws + off_xp);

  (void)hipMemsetAsync(d_ws, 0, 4096, stream);
  hipLaunchKernelGGL(k_transpose, dim3(157, 48), dim3(32, 8), 0, stream, Wih, WihT);
  hipLaunchKernelGGL(k_cvt_wout, dim3((NPAD * HID / 4 + 255) / 256), dim3(256), 0, stream, Wout, WoutP);
  hipLaunchKernelGGL(k_gather, dim3(SEQ_ * B_), dim3(256), 0, stream, X, WihT, bih, xp);
  hipLaunchKernelGGL(k_rec, dim3(NREC), dim3(256), 0, stream,
                     Whh, bhh, state, xp, hbuf, Ybuf, hT, flags);
  hipLaunchKernelGGL(k_outgemm, dim3(128, 40), dim3(256), 0, stream, Ybuf, WoutP, bout, out);
}

// Round 10
// 1381.211 us; speedup vs baseline: 5945.1504x; 1.0444x over previous
//
#include <hip/hip_runtime.h>

typedef __attribute__((ext_vector_type(8))) short bf16x8;
typedef __attribute__((ext_vector_type(4))) float f32x4;
typedef __attribute__((ext_vector_type(4))) int i32x4;
typedef unsigned short ushort_t;
typedef unsigned int uint_t;

#define VOCAB 5000
#define HID   512
#define B_    64
#define SEQ_  256
#define H3    1536
#define NPAD  5120
#define NREC  32
#define NGEM  224
#define NTILE (SEQ_ * 40)

__device__ __forceinline__ ushort_t f2bf(float f){
  uint_t u = __float_as_uint(f);
  u = u + 0x7fffu + ((u >> 16) & 1u);
  return (ushort_t)(u >> 16);
}
__device__ __forceinline__ float bf2f(ushort_t s){
  return __uint_as_float(((uint_t)s) << 16);
}

// ---- agent-scope (sc1) helpers: the PROVEN cross-XCD visible flavor (R2/R5/R9) ----
__device__ __forceinline__ uint_t agent_load_u32(const uint_t* p){
  uint_t v;
  asm volatile("global_load_dword %0, %1, off sc1\n\t"
               "s_waitcnt vmcnt(0)" : "=v"(v) : "v"(p) : "memory");
  return v;
}
__device__ __forceinline__ void agent_store_u32(uint_t* p, uint_t v){
  asm volatile("global_store_dword %0, %1, off sc1" :: "v"(p), "v"(v) : "memory");
}
__device__ __forceinline__ void agent_store_u16(ushort_t* p, ushort_t v){
  uint_t vv = v;
  asm volatile("global_store_short %0, %1, off sc1" :: "v"(p), "v"(vv) : "memory");
}

// ---------------- P1: transpose W_ih (1536 x 5000) -> W_ihT (5000 x 1536) ----------
__global__ void k_transpose(const float* __restrict__ W, float* __restrict__ WT){
  __shared__ float tile[32][33];
  const int bv = blockIdx.x * 32;   // vocab
  const int bg = blockIdx.y * 32;   // 3H
  const int tx = threadIdx.x, ty = threadIdx.y; // 32x8
  #pragma unroll
  for(int r = 0; r < 32; r += 8){
    int g = bg + ty + r, v = bv + tx;
    tile[ty + r][tx] = (v < VOCAB) ? W[(size_t)g * VOCAB + v] : 0.f;
  }
  __syncthreads();
  #pragma unroll
  for(int r = 0; r < 32; r += 8){
    int v = bv + ty + r, g = bg + tx;
    if(v < VOCAB) WT[(size_t)v * H3 + g] = tile[tx][ty + r];
  }
}

// ---------------- P1b: W_out (5000x512) -> bf16 padded (5120x512) ------------------
__global__ void k_cvt_wout(const float* __restrict__ W, ushort_t* __restrict__ WP){
  int idx = (blockIdx.x * 256 + threadIdx.x) * 4;
  if(idx >= NPAD * HID) return;
  float x0 = 0.f, x1 = 0.f, x2 = 0.f, x3 = 0.f;
  if(idx < VOCAB * HID){
    const float4 v = *(const float4*)(W + idx);
    x0 = v.x; x1 = v.y; x2 = v.z; x3 = v.w;
  }
  ushort4 o; o.x = f2bf(x0); o.y = f2bf(x1); o.z = f2bf(x2); o.w = f2bf(x3);
  *(ushort4*)(WP + idx) = o;
}

// ---------------- P2: gather x_proj[s,b,:] = W_ihT[X[b,s]] + b_ih  (bf16 out) ------
__global__ void k_gather(const int* __restrict__ X, const float* __restrict__ WT,
                         const float* __restrict__ bih, ushort_t* __restrict__ xp){
  const int sb = blockIdx.x;            // s*64 + b
  const int s = sb >> 6, b = sb & 63;
  const int x = X[b * SEQ_ + s];
  const float4* src = (const float4*)(WT + (size_t)x * H3);
  const float4* bi  = (const float4*)bih;
  for(int i = threadIdx.x; i < H3 / 4; i += 256){
    float4 v = src[i], c = bi[i];
    ushort4 o;
    o.x = f2bf(v.x + c.x); o.y = f2bf(v.y + c.y);
    o.z = f2bf(v.z + c.z); o.w = f2bf(v.w + c.w);
    ((ushort4*)(xp + (size_t)sb * H3))[i] = o;
  }
}

// ---------------- mega: 32 rec blocks (R9 protocol) + 224 gem consumers ------------
// rec: R9 exactly, except Y[t] is published via sc1 stores drained BEFORE the flag,
// so flag>=t+2 guarantees Y[t] visible at MALL. gem: block gb takes tiles gb+k*224
// (tile = t*40+n, 64x128 out), polls all 32 flags (wave 0, sleepy), stages Y[t] via
// sc1 into LDS, B from cached WP, writes out with bias.
__global__ void __launch_bounds__(256, 1) k_mega(
    const float* __restrict__ Whh, const float* __restrict__ bhh,
    const float* __restrict__ state, const ushort_t* __restrict__ xp,
    const ushort_t* __restrict__ WP, const float* __restrict__ bout,
    ushort_t* __restrict__ hbuf, ushort_t* __restrict__ Y,
    float* __restrict__ out, float* __restrict__ hT, uint_t* flags)
{
  __shared__ __align__(16) char smem[100352];
  const int bid = blockIdx.x, tid = threadIdx.x;
  const int lane = tid & 63, wv = tid >> 6;
  const int l15 = lane & 15, lhi = lane >> 4;

  if(bid < NREC){
    // ================= recurrence role (R9 protocol) =================
    ushort_t (*Wl)[520] = (ushort_t(*)[520])smem;
    float* bl = (float*)(smem + 96 * 520 * 2);
    const int g = bid;
    const int dom = g >> 4, sub = g & 15;
    const int jb = sub * 32;

    for(int idx = tid; idx < 96 * 512; idx += 256){
      int r = idx >> 9, c = idx & 511;
      int jgr = r / 48, rem = r % 48;
      int gate = rem >> 4, jl = jgr * 16 + (rem & 15);
      Wl[r][c] = f2bf(Whh[((size_t)(gate * HID + jb + jl)) * HID + c]);
    }
    if(tid < 96){
      int jgr = tid / 48, rem = tid % 48;
      int gate = rem >> 4, jl = jgr * 16 + (rem & 15);
      bl[tid] = bhh[gate * HID + jb + jl];
    }

    const int jg = wv >> 1;
    const int j  = jb + jg * 16 + l15;
    const int rbase = jg * 48;
    const int bband = dom * 32 + (wv & 1) * 16;

    float hprev[4]; int brow[4];
    #pragma unroll
    for(int i = 0; i < 4; i++){
      brow[i] = bband + lhi * 4 + i;
      hprev[i] = state[brow[i] * HID + j];
    }

    #pragma unroll
    for(int i = 0; i < 4; i++) agent_store_u16(hbuf + brow[i] * HID + j, f2bf(hprev[i]));
    asm volatile("s_waitcnt vmcnt(0)" ::: "memory");
    __syncthreads();
    if(tid == 0) agent_store_u32(flags + g * 32, 1u);

    const int fidx = dom * 16 + ((lane + sub) & 15);

    for(int t = 0; t < SEQ_; ++t){
      const ushort_t* hin  = hbuf + (t & 1) * (B_ * HID);
      ushort_t*       hout = hbuf + ((t + 1) & 1) * (B_ * HID);

      // gi prefetch (bf16 xp, cached)
      float gir[4], giz[4], gin_[4];
      const ushort_t* xr = xp + (size_t)t * B_ * H3;
      #pragma unroll
      for(int i = 0; i < 4; i++){
        const ushort_t* p = xr + (size_t)brow[i] * H3 + j;
        gir[i] = bf2f(p[0]); giz[i] = bf2f(p[HID]); gin_[i] = bf2f(p[2 * HID]);
      }

      // every wave polls all 16 domain flags itself (no barrier after)
      if(lane < 16){
        const uint_t need = (uint_t)(t + 1);
        int gd = 0;
        while(agent_load_u32(flags + fidx * 32) < need){
          __builtin_amdgcn_s_sleep(1);
          if(++gd > 200000) break;
        }
      }

      // read h^t from the coherence point
      i32x4 tmp[16];
      const char* abase = (const char*)(hin + (size_t)(bband + l15) * HID + 8 * lhi);
      #define LDH(i, off) asm volatile("global_load_dwordx4 %0, %1, off offset:" #off " sc1" \
                                       : "=v"(tmp[i]) : "v"(abase) : "memory");
      LDH(0,0)   LDH(1,64)   LDH(2,128)  LDH(3,192)
      LDH(4,256) LDH(5,320)  LDH(6,384)  LDH(7,448)
      LDH(8,512) LDH(9,576)  LDH(10,640) LDH(11,704)
      LDH(12,768) LDH(13,832) LDH(14,896) LDH(15,960)
      #undef LDH
      asm volatile("s_waitcnt vmcnt(0)" ::: "memory");
      __builtin_amdgcn_sched_barrier(0);

      f32x4 acc0 = {0.f,0.f,0.f,0.f}, acc1 = {0.f,0.f,0.f,0.f}, acc2 = {0.f,0.f,0.f,0.f};
      #pragma unroll
      for(int kk = 0; kk < 16; kk++){
        bf16x8 a = __builtin_bit_cast(bf16x8, tmp[kk]);
        const int kc = kk * 32 + 8 * lhi;
        bf16x8 b0 = *(const bf16x8*)&Wl[rbase + l15][kc];
        bf16x8 b1 = *(const bf16x8*)&Wl[rbase + 16 + l15][kc];
        bf16x8 b2 = *(const bf16x8*)&Wl[rbase + 32 + l15][kc];
        acc0 = __builtin_amdgcn_mfma_f32_16x16x32_bf16(a, b0, acc0, 0, 0, 0);
        acc1 = __builtin_amdgcn_mfma_f32_16x16x32_bf16(a, b1, acc1, 0, 0, 0);
        acc2 = __builtin_amdgcn_mfma_f32_16x16x32_bf16(a, b2, acc2, 0, 0, 0);
      }

      const float cr = bl[rbase + l15], cz = bl[rbase + 16 + l15], cn = bl[rbase + 32 + l15];
      float hn4[4];
      #pragma unroll
      for(int i = 0; i < 4; i++){
        float r = 1.f / (1.f + expf(-(gir[i] + acc0[i] + cr)));
        float z = 1.f / (1.f + expf(-(giz[i] + acc1[i] + cz)));
        float n = tanhf(gin_[i] + r * (acc2[i] + cn));
        hn4[i] = (1.f - z) * n + z * hprev[i];
        hprev[i] = hn4[i];
        ushort_t hb = f2bf(hn4[i]);
        agent_store_u16(hout + (size_t)brow[i] * HID + j, hb);
        // Y published sc1 too: must be MALL-visible when flag hits t+2
        agent_store_u16(Y + (size_t)t * B_ * HID + (size_t)brow[i] * HID + j, hb);
      }
      asm volatile("s_waitcnt vmcnt(0)" ::: "memory");   // drain h + Y stores
      __syncthreads();                                    // single barrier per step
      if(tid == 0) agent_store_u32(flags + g * 32, (uint_t)(t + 2));

      if(t == SEQ_ - 1){
        #pragma unroll
        for(int i = 0; i < 4; i++) hT[brow[i] * HID + j] = hn4[i];
      }
    }
  } else {
    // ================= out-GEMM role =================
    ushort_t (*At)[520] = (ushort_t(*)[520])smem;
    const int gb = bid - NREC;

    for(int tile = gb; tile < NTILE; tile += NGEM){
      const int t = tile / 40, n0 = (tile % 40) * 128;

      // wave 0 polls all 32 flags >= t+2 with sleepy backoff
      if(wv == 0){
        const uint_t need = (uint_t)(t + 2);
        int gd = 0;
        while(true){
          uint_t v = 0xffffffffu;
          if(lane < 32) v = agent_load_u32(flags + lane * 32);
          if(__all(v >= need)) break;
          __builtin_amdgcn_s_sleep(64);
          if(++gd > 2000000) break;   // fail loud instead of hanging
        }
      }
      __syncthreads();

      // stage A = Y[t] (64 x 512 bf16) into LDS via sc1 loads (MALL-fresh)
      {
        const int row = tid >> 2, q = tid & 3;
        const char* src = (const char*)(Y + (size_t)t * B_ * HID) + row * 1024 + q * 256;
        i32x4 tv[16];
        #define LDA(i, off) asm volatile("global_load_dwordx4 %0, %1, off offset:" #off " sc1" \
                                         : "=v"(tv[i]) : "v"(src) : "memory");
        LDA(0,0)   LDA(1,16)  LDA(2,32)  LDA(3,48)
        LDA(4,64)  LDA(5,80)  LDA(6,96)  LDA(7,112)
        LDA(8,128) LDA(9,144) LDA(10,160) LDA(11,176)
        LDA(12,192) LDA(13,208) LDA(14,224) LDA(15,240)
        #undef LDA
        asm volatile("s_waitcnt vmcnt(0)" ::: "memory");
        __builtin_amdgcn_sched_barrier(0);
        #pragma unroll
        for(int i = 0; i < 16; i++) *(i32x4*)&At[row][q * 128 + i * 8] = tv[i];
      }
      __syncthreads();

      f32x4 acc[4][2];
      #pragma unroll
      for(int a = 0; a < 4; a++){ acc[a][0] = (f32x4){0,0,0,0}; acc[a][1] = (f32x4){0,0,0,0}; }

      const ushort_t* B0 = WP + (size_t)(n0 + wv * 32 + l15) * HID;
      const ushort_t* B1 = WP + (size_t)(n0 + wv * 32 + 16 + l15) * HID;
      #pragma unroll
      for(int kt = 0; kt < 16; kt++){
        const int kc = kt * 32 + 8 * lhi;
        bf16x8 b0 = *(const bf16x8*)(B0 + kc);
        bf16x8 b1 = *(const bf16x8*)(B1 + kc);
        bf16x8 a0 = *(const bf16x8*)&At[0 * 16 + l15][kc];
        bf16x8 a1 = *(const bf16x8*)&At[1 * 16 + l15][kc];
        bf16x8 a2 = *(const bf16x8*)&At[2 * 16 + l15][kc];
        bf16x8 a3 = *(const bf16x8*)&At[3 * 16 + l15][kc];
        acc[0][0] = __builtin_amdgcn_mfma_f32_16x16x32_bf16(a0, b0, acc[0][0], 0, 0, 0);
        acc[0][1] = __builtin_amdgcn_mfma_f32_16x16x32_bf16(a0, b1, acc[0][1], 0, 0, 0);
        acc[1][0] = __builtin_amdgcn_mfma_f32_16x16x32_bf16(a1, b0, acc[1][0], 0, 0, 0);
        acc[1][1] = __builtin_amdgcn_mfma_f32_16x16x32_bf16(a1, b1, acc[1][1], 0, 0, 0);
        acc[2][0] = __builtin_amdgcn_mfma_f32_16x16x32_bf16(a2, b0, acc[2][0], 0, 0, 0);
        acc[2][1] = __builtin_amdgcn_mfma_f32_16x16x32_bf16(a2, b1, acc[2][1], 0, 0, 0);
        acc[3][0] = __builtin_amdgcn_mfma_f32_16x16x32_bf16(a3, b0, acc[3][0], 0, 0, 0);
        acc[3][1] = __builtin_amdgcn_mfma_f32_16x16x32_bf16(a3, b1, acc[3][1], 0, 0, 0);
      }

      #pragma unroll
      for(int mi = 0; mi < 4; mi++){
        #pragma unroll
        for(int ni = 0; ni < 2; ni++){
          const int v = n0 + wv * 32 + ni * 16 + l15;
          if(v < VOCAB){
            const float bb = bout[v];
            #pragma unroll
            for(int i = 0; i < 4; i++){
              const int sb = t * 64 + mi * 16 + lhi * 4 + i;
              out[(size_t)sb * VOCAB + v] = acc[mi][ni][i] + bb;
            }
          }
        }
      }
      __syncthreads();  // all waves done with At before next tile restages
    }
  }
}

extern "C" void kernel_launch(void* const* d_in, const int* in_sizes, int n_in,
                              void* d_out, int out_size, void* d_ws, size_t ws_size,
                              hipStream_t stream)
{
  const int*   X     = (const int*)  d_in[0];
  const float* state = (const float*)d_in[1];
  const float* Wih   = (const float*)d_in[2];
  const float* Whh   = (const float*)d_in[3];
  const float* bih   = (const float*)d_in[4];
  const float* bhh   = (const float*)d_in[5];
  const float* Wout  = (const float*)d_in[6];
  const float* bout  = (const float*)d_in[7];
  float* out = (float*)d_out;
  float* hT  = out + (size_t)SEQ_ * B_ * VOCAB;

  char* ws = (char*)d_ws;
  const size_t off_WihT  = 4096;
  const size_t off_WoutP = off_WihT  + (size_t)VOCAB * H3  * sizeof(float);
  const size_t off_Y     = off_WoutP + (size_t)NPAD  * HID * sizeof(ushort_t);
  const size_t off_h     = off_Y     + (size_t)SEQ_ * B_ * HID * sizeof(ushort_t);
  const size_t off_xp    = off_h     + (size_t)2 * B_ * HID * sizeof(ushort_t);

  uint_t*   flags = (uint_t*)  ws;                 // 32 flags, 128B apart (4KB)
  float*    WihT  = (float*)   (ws + off_WihT);
  ushort_t* WoutP = (ushort_t*)(ws + off_WoutP);
  ushort_t* Ybuf  = (ushort_t*)(ws + off_Y);
  ushort_t* hbuf  = (ushort_t*)(ws + off_h);
  ushort_t* xp    = (ushort_t*)(ws + off_xp);

  (void)hipMemsetAsync(d_ws, 0, 4096, stream);
  hipLaunchKernelGGL(k_transpose, dim3(157, 48), dim3(32, 8), 0, stream, Wih, WihT);
  hipLaunchKernelGGL(k_cvt_wout, dim3((NPAD * HID / 4 + 255) / 256), dim3(256), 0, stream, Wout, WoutP);
  hipLaunchKernelGGL(k_gather, dim3(SEQ_ * B_), dim3(256), 0, stream, X, WihT, bih, xp);
  hipLaunchKernelGGL(k_mega, dim3(NREC + NGEM), dim3(256), 0, stream,
                     Whh, bhh, state, xp, WoutP, bout, hbuf, Ybuf, out, hT, flags);
}